// Round 10
// baseline (15213.826 us; speedup 1.0000x reference)
//
#include <hip/hip_runtime.h>

#define B_ 128
#define S_ 4096
#define IN_ 6
#define N_ 64
#define MOT_ 3
#define UNF 6
#define EPS_ 1e-8f
#define LOG2E 1.4426950408889634f

typedef float v2f __attribute__((ext_vector_type(2)));

// ---- VALU-pipe cross-lane pair-sums over lane bits 4 and 5 ----
__device__ __forceinline__ float red16(float x) {
#if __has_builtin(__builtin_amdgcn_permlane16_swap)
    auto r = __builtin_amdgcn_permlane16_swap(__float_as_int(x), __float_as_int(x),
                                              false, false);
    return __int_as_float((int)r[0]) + __int_as_float((int)r[1]);
#else
    return x + __shfl_xor(x, 16, 64);
#endif
}
__device__ __forceinline__ float red32(float x) {
#if __has_builtin(__builtin_amdgcn_permlane32_swap)
    auto r = __builtin_amdgcn_permlane32_swap(__float_as_int(x), __float_as_int(x),
                                              false, false);
    return __int_as_float((int)r[0]) + __int_as_float((int)r[1]);
#else
    return x + __shfl_xor(x, 32, 64);
#endif
}

// barrier with LDS-only drain (no vmcnt: global loads/stores stay in flight)
__device__ __forceinline__ void lds_barrier() {
    asm volatile("s_waitcnt lgkmcnt(0)" ::: "memory");
    __builtin_amdgcn_s_barrier();
}

// TWO chains per block at WAVE granularity (TLP, not r6's failed in-stream
// ILP): 512 threads = 8 waves; chain ch = w>>2 uses waves {ch*4..ch*4+3}.
// HW round-robins waves to SIMDs, so each SIMD hosts one wave of EACH chain:
// while one chain stalls on its serial unfold path (LDS latency, trans deps,
// barrier), the other chain's wave issues. Block-wide s_barrier keeps both
// chains phase-locked; within a phase their work is independent.
// Per chain: subwave sw owns columns sw*16..sw*16+15; lane = (cc=l>>4 j-chunk,
// ii=l&15 col); 16 sigmoids/lane (packed-f32 math), 2-stage permlane
// butterfly, per-lane register sensory, ONE lgkm-only barrier per unfold.
__launch_bounds__(512, 1)
__global__ void ltc_kernel(
    const float* __restrict__ x,
    const float* __restrict__ mean_us, const float* __restrict__ std_us,
    const float* __restrict__ input_w, const float* __restrict__ input_b,
    const float* __restrict__ output_w, const float* __restrict__ output_b,
    const float* __restrict__ gleak, const float* __restrict__ vleak,
    const float* __restrict__ cm,
    const float* __restrict__ sW, const float* __restrict__ sMu,
    const float* __restrict__ sSig, const float* __restrict__ sErev,
    const float* __restrict__ W, const float* __restrict__ Mu,
    const float* __restrict__ Sig, const float* __restrict__ Erev,
    float* __restrict__ out)
{
    const int t    = threadIdx.x;
    const int lane = t & 63;
    const int w    = t >> 6;      // wave 0..7
    const int ch   = w >> 2;      // chain 0/1
    const int sw   = w & 3;       // subwave within chain
    const int cc   = lane >> 4;   // j-chunk 0..3 (16 j's each)
    const int ii   = lane & 15;   // column within subwave's block
    const int myCol = sw * 16 + ii;
    const int jb   = cc * 16;

    __shared__ __align__(16) float vbuf[2][2][N_];   // [chain][parity][col]

    // --- recurrent synapse params: 16 synapses (j=jb..jb+15) of column myCol,
    // packed in pairs for v_pk_fma: sigmoid((v-mu)*sig) = 1/(1+exp2(v*A + Bc))
    v2f A2[8], B2[8];
    float Wr[16], We[16];
#pragma unroll
    for (int jj = 0; jj < 16; ++jj) {
        int idx = (jb + jj) * N_ + myCol;
        float sg = Sig[idx], m = Mu[idx], ww = W[idx], e = Erev[idx];
        A2[jj >> 1][jj & 1] = -sg * LOG2E;
        B2[jj >> 1][jj & 1] = m * sg * LOG2E;
        Wr[jj] = ww;
        We[jj] = ww * e;
    }

    // --- per-column state consts ---
    const float cmt = cm[myCol] * (float)UNF;
    const float glk = gleak[myCol];
    const float gv  = glk * vleak[myCol];
    const float dbase = cmt + glk + EPS_;

    // --- sensory params: per-lane, ALL 6 inputs for column myCol ---
    float SA[IN_], SB[IN_], SWe[IN_], SWv[IN_], NS[IN_], NB[IN_];
#pragma unroll
    for (int ci = 0; ci < IN_; ++ci) {
        int idx = ci * N_ + myCol;
        float sg = sSig[idx], m = sMu[idx], ww = sW[idx], e = sErev[idx];
        SA[ci]  = -sg * LOG2E;
        SB[ci]  = m * sg * LOG2E;
        SWv[ci] = ww;
        SWe[ci] = ww * e;
        NS[ci]  = input_w[ci] / std_us[ci];
        NB[ci]  = input_b[ci] - mean_us[ci] / std_us[ci] * input_w[ci];
    }

    // --- output consts (chain's wave 0, lanes 0..2 hold motor columns) ---
    float OW = 0.f, OB = 0.f;
    if (myCol < MOT_) {
        OW = output_w[myCol] * std_us[myCol];
        OB = output_b[myCol] * std_us[myCol] + mean_us[myCol];
    }

    const int b = blockIdx.x * 2 + ch;
    const float* xb = x + (size_t)b * S_ * IN_;
    float* ob = out + (size_t)b * S_ * MOT_;

    if (lane < 16) vbuf[ch][0][sw * 16 + lane] = 0.f;

    // step-0 inputs (one-time); force VMEM via VGPR offset
    float xc[IN_];
    {
        int off = 0;
        asm volatile("" : "+v"(off));
        float2 x01 = *(const float2*)(xb + off);
        float2 x23 = *(const float2*)(xb + off + 2);
        float2 x45 = *(const float2*)(xb + off + 4);
        xc[0] = x01.x; xc[1] = x01.y; xc[2] = x23.x;
        xc[3] = x23.y; xc[4] = x45.x; xc[5] = x45.y;
    }
    __syncthreads();

    float v_my = 0.f;

    for (int s = 0; s < S_; ++s) {
        // prefetch next step's inputs (VMEM, stays in flight across lgkm waits)
        const int s1 = (s + 1 < S_) ? (s + 1) : s;
        int off = s1 * IN_;
        asm volatile("" : "+v"(off));
        float2 p01 = *(const float2*)(xb + off);
        float2 p23 = *(const float2*)(xb + off + 2);
        float2 p45 = *(const float2*)(xb + off + 4);

        // per-lane sensory fold for this step (registers only; consumed only
        // after k=0's butterfly -> overlaps k=0's v-read + sigmoid phase)
        float wns = 0.f, wds = 0.f;
#pragma unroll
        for (int ci = 0; ci < IN_; ++ci) {
            float u  = fmaf(xc[ci], NS[ci], NB[ci]);
            float e  = __builtin_amdgcn_exp2f(fmaf(u, SA[ci], SB[ci]));
            float sg = __builtin_amdgcn_rcpf(1.0f + e);
            wns = fmaf(SWe[ci], sg, wns);
            wds = fmaf(SWv[ci], sg, wds);
        }
        const float nbs = gv + wns;
        const float dbs = dbase + wds;

#pragma unroll
        for (int k = 0; k < UNF; ++k) {
            const int p = k & 1;
            // broadcast-read the 16 v's of this lane's j-chunk (4x ds_read_b128)
            float4 q0 = *(const float4*)&vbuf[ch][p][jb];
            float4 q1 = *(const float4*)&vbuf[ch][p][jb + 4];
            float4 q2 = *(const float4*)&vbuf[ch][p][jb + 8];
            float4 q3 = *(const float4*)&vbuf[ch][p][jb + 12];
            const v2f vp[8] = {
                {q0.x, q0.y}, {q0.z, q0.w}, {q1.x, q1.y}, {q1.z, q1.w},
                {q2.x, q2.y}, {q2.z, q2.w}, {q3.x, q3.y}, {q3.z, q3.w}};

            float pn0 = 0.f, pd0 = 0.f, pn1 = 0.f, pd1 = 0.f;
#pragma unroll
            for (int pi = 0; pi < 8; ++pi) {
                v2f z  = __builtin_elementwise_fma(vp[pi], A2[pi], B2[pi]); // pk_fma
                v2f e  = {__builtin_amdgcn_exp2f(z.x), __builtin_amdgcn_exp2f(z.y)};
                v2f tt = e + 1.0f;                                          // pk_add
                float s0  = __builtin_amdgcn_rcpf(tt.x);
                float s1x = __builtin_amdgcn_rcpf(tt.y);
                pn0 = fmaf(We[2*pi],   s0,  pn0);
                pd0 = fmaf(Wr[2*pi],   s0,  pd0);
                pn1 = fmaf(We[2*pi+1], s1x, pn1);
                pd1 = fmaf(Wr[2*pi+1], s1x, pd1);
            }
            float pn = pn0 + pn1;
            float pd = pd0 + pd1;

            // VALU butterfly over cc (lane bits 4,5): full column sums
            pn = red16(pn);  pd = red16(pd);
            pn = red32(pn);  pd = red32(pd);

            v_my = fmaf(cmt, v_my, nbs + pn) * __builtin_amdgcn_rcpf(dbs + pd);

            // publish v for next unfold (double-buffered, one writer per column)
            if (lane < 16) vbuf[ch][p ^ 1][sw * 16 + lane] = v_my;

            lds_barrier();
        }

        // rotate prefetched inputs; motor outputs from chain's wave 0
        xc[0] = p01.x; xc[1] = p01.y; xc[2] = p23.x;
        xc[3] = p23.y; xc[4] = p45.x; xc[5] = p45.y;
        if (sw == 0 && lane < MOT_) ob[s * MOT_ + lane] = fmaf(v_my, OW, OB);
    }
}

extern "C" void kernel_launch(void* const* d_in, const int* in_sizes, int n_in,
                              void* d_out, int out_size, void* d_ws, size_t ws_size,
                              hipStream_t stream) {
    (void)in_sizes; (void)n_in; (void)d_ws; (void)ws_size; (void)out_size;
    const float* x       = (const float*)d_in[0];
    const float* mean_us = (const float*)d_in[1];
    const float* std_us  = (const float*)d_in[2];
    const float* input_w = (const float*)d_in[3];
    const float* input_b = (const float*)d_in[4];
    const float* out_w   = (const float*)d_in[5];
    const float* out_b   = (const float*)d_in[6];
    const float* gleak   = (const float*)d_in[7];
    const float* vleak   = (const float*)d_in[8];
    const float* cm      = (const float*)d_in[9];
    const float* sW      = (const float*)d_in[10];
    const float* sMu     = (const float*)d_in[11];
    const float* sSig    = (const float*)d_in[12];
    const float* sErev   = (const float*)d_in[13];
    const float* W       = (const float*)d_in[14];
    const float* Mu      = (const float*)d_in[15];
    const float* Sig     = (const float*)d_in[16];
    const float* Erev    = (const float*)d_in[17];
    float* out = (float*)d_out;

    ltc_kernel<<<dim3(B_ / 2), dim3(512), 0, stream>>>(
        x, mean_us, std_us, input_w, input_b, out_w, out_b,
        gleak, vleak, cm, sW, sMu, sSig, sErev, W, Mu, Sig, Erev, out);
}

// Round 11
// 9917.608 us; speedup vs baseline: 1.5340x; 1.5340x over previous
//
#include <hip/hip_runtime.h>

#define B_ 128
#define S_ 4096
#define IN_ 6
#define N_ 64
#define MOT_ 3
#define UNF 6
#define EPS_ 1e-8f
#define LOG2E 1.4426950408889634f

typedef float v2f __attribute__((ext_vector_type(2)));

// ---- VALU-pipe cross-lane pair-sums over lane bits 4 and 5 ----
__device__ __forceinline__ float red16(float x) {
#if __has_builtin(__builtin_amdgcn_permlane16_swap)
    auto r = __builtin_amdgcn_permlane16_swap(__float_as_int(x), __float_as_int(x),
                                              false, false);
    return __int_as_float((int)r[0]) + __int_as_float((int)r[1]);
#else
    return x + __shfl_xor(x, 16, 64);
#endif
}
__device__ __forceinline__ float red32(float x) {
#if __has_builtin(__builtin_amdgcn_permlane32_swap)
    auto r = __builtin_amdgcn_permlane32_swap(__float_as_int(x), __float_as_int(x),
                                              false, false);
    return __int_as_float((int)r[0]) + __int_as_float((int)r[1]);
#else
    return x + __shfl_xor(x, 32, 64);
#endif
}

__device__ __forceinline__ float bperm(int addr, float v) {
    return __int_as_float(__builtin_amdgcn_ds_bpermute(addr, __float_as_int(v)));
}

// barrier with LDS-only drain (no vmcnt: global loads/stores stay in flight)
__device__ __forceinline__ void lds_barrier() {
    asm volatile("s_waitcnt lgkmcnt(0)" ::: "memory");
    __builtin_amdgcn_s_barrier();
}

// One workgroup per batch chain. 256 threads = 4 waves = 1 wave/SIMD.
// Wave w owns columns w*16..w*16+15; lane l=(cc=l>>4, ii=l&15), col=16w+ii.
// j-set per lane: {16q + 4cc + r}, q = (w+d)&3 for d=0..3 — so each remote
// wave's 4 v's are ONE aligned float4 in vbuf, and the OWN wave's quad (d=0)
// is gathered from registers via 4 ds_bpermute issued inside the
// write->drain->barrier window of the previous unfold (latency hidden).
// Next unfold: issue the 3 remote float4 reads, compute the own-quad's 4
// sigmoids from registers WHILE the reads are in flight (read latency
// hidden), then the 12 remote sigmoids, 2-stage permlane butterfly, update.
// ONE lgkm-only barrier per unfold. Sensory per-lane in registers (r9).
__launch_bounds__(256, 1)
__global__ void ltc_kernel(
    const float* __restrict__ x,
    const float* __restrict__ mean_us, const float* __restrict__ std_us,
    const float* __restrict__ input_w, const float* __restrict__ input_b,
    const float* __restrict__ output_w, const float* __restrict__ output_b,
    const float* __restrict__ gleak, const float* __restrict__ vleak,
    const float* __restrict__ cm,
    const float* __restrict__ sW, const float* __restrict__ sMu,
    const float* __restrict__ sSig, const float* __restrict__ sErev,
    const float* __restrict__ W, const float* __restrict__ Mu,
    const float* __restrict__ Sig, const float* __restrict__ Erev,
    float* __restrict__ out)
{
    const int b    = blockIdx.x;
    const int t    = threadIdx.x;
    const int lane = t & 63;
    const int w    = t >> 6;      // wave 0..3
    const int cc   = lane >> 4;   // j-subchunk 0..3
    const int ii   = lane & 15;   // column within wave's block
    const int myCol = (w << 4) + ii;
    const int cc4  = cc << 2;

    __shared__ __align__(16) float vbuf[2][N_];

    // --- recurrent synapse params: slot m=4d+r -> j = 16*((w+d)&3) + 4cc + r
    // sigmoid((v-mu)*sig) = 1/(1+exp2(v*A + Bc)), A=-sig*log2e, Bc=mu*sig*log2e
    v2f A2[8], B2[8];
    float Wr[16], We[16];
#pragma unroll
    for (int d = 0; d < 4; ++d) {
        const int q  = (w + d) & 3;
        const int j0 = (q << 4) + cc4;
#pragma unroll
        for (int r = 0; r < 4; ++r) {
            int idx = (j0 + r) * N_ + myCol;
            float sg = Sig[idx], m = Mu[idx], ww = W[idx], e = Erev[idx];
            const int mm = 4 * d + r;
            A2[mm >> 1][mm & 1] = -sg * LOG2E;
            B2[mm >> 1][mm & 1] = m * sg * LOG2E;
            Wr[mm] = ww;
            We[mm] = ww * e;
        }
    }

    // --- per-column state consts ---
    const float cmt = cm[myCol] * (float)UNF;
    const float glk = gleak[myCol];
    const float gv  = glk * vleak[myCol];
    const float dbase = cmt + glk + EPS_;

    // --- sensory params: per-lane, ALL 6 inputs for column myCol ---
    float SA[IN_], SB[IN_], SWe[IN_], SWv[IN_], NS[IN_], NB[IN_];
#pragma unroll
    for (int ci = 0; ci < IN_; ++ci) {
        int idx = ci * N_ + myCol;
        float sg = sSig[idx], m = sMu[idx], ww = sW[idx], e = sErev[idx];
        SA[ci]  = -sg * LOG2E;
        SB[ci]  = m * sg * LOG2E;
        SWv[ci] = ww;
        SWe[ci] = ww * e;
        NS[ci]  = input_w[ci] / std_us[ci];
        NB[ci]  = input_b[ci] - mean_us[ci] / std_us[ci] * input_w[ci];
    }

    // --- output consts (lanes 0..2 of wave 0 hold motor columns 0..2) ---
    float OW = 0.f, OB = 0.f;
    if (t < MOT_) {
        OW = output_w[t] * std_us[t];
        OB = output_b[t] * std_us[t] + mean_us[t];
    }

    const float* xb = x + (size_t)b * S_ * IN_;
    float* ob = out + (size_t)b * S_ * MOT_;

    if (lane < 16) vbuf[0][(w << 4) + lane] = 0.f;
    float ov0 = 0.f, ov1 = 0.f, ov2 = 0.f, ov3 = 0.f;   // own-quad v (regs)

    // bpermute gather addresses (constant per lane): source lanes 4cc+r
    const int bp0 = (cc4 + 0) << 2, bp1 = (cc4 + 1) << 2;
    const int bp2 = (cc4 + 2) << 2, bp3 = (cc4 + 3) << 2;
    // remote read offsets (constant per lane)
    const int ro1 = (((w + 1) & 3) << 4) + cc4;
    const int ro2 = (((w + 2) & 3) << 4) + cc4;
    const int ro3 = (((w + 3) & 3) << 4) + cc4;

    // step-0 inputs (one-time); force VMEM via VGPR offset
    float xc[IN_];
    {
        int off = 0;
        asm volatile("" : "+v"(off));
        float2 x01 = *(const float2*)(xb + off);
        float2 x23 = *(const float2*)(xb + off + 2);
        float2 x45 = *(const float2*)(xb + off + 4);
        xc[0] = x01.x; xc[1] = x01.y; xc[2] = x23.x;
        xc[3] = x23.y; xc[4] = x45.x; xc[5] = x45.y;
    }
    __syncthreads();

    float v_my = 0.f;

    for (int s = 0; s < S_; ++s) {
        // prefetch next step's inputs (VMEM, stays in flight across lgkm waits)
        const int s1 = (s + 1 < S_) ? (s + 1) : s;
        int off = s1 * IN_;
        asm volatile("" : "+v"(off));
        float2 p01 = *(const float2*)(xb + off);
        float2 p23 = *(const float2*)(xb + off + 2);
        float2 p45 = *(const float2*)(xb + off + 4);

        // per-lane sensory fold (registers only)
        float wns = 0.f, wds = 0.f;
#pragma unroll
        for (int ci = 0; ci < IN_; ++ci) {
            float u  = fmaf(xc[ci], NS[ci], NB[ci]);
            float e  = __builtin_amdgcn_exp2f(fmaf(u, SA[ci], SB[ci]));
            float sg = __builtin_amdgcn_rcpf(1.0f + e);
            wns = fmaf(SWe[ci], sg, wns);
            wds = fmaf(SWv[ci], sg, wds);
        }
        const float nbs = gv + wns;
        const float dbs = dbase + wds;
        float cv = fmaf(cmt, v_my, nbs);   // k=0 numerator base

#pragma unroll
        for (int k = 0; k < UNF; ++k) {
            const int p = k & 1;
            // issue the 3 REMOTE quad reads first (latency overlapped below)
            float4 r1 = *(const float4*)&vbuf[p][ro1];
            float4 r2 = *(const float4*)&vbuf[p][ro2];
            float4 r3 = *(const float4*)&vbuf[p][ro3];

            // own-quad sigmoids (d=0) from registers — no LDS wait
            float pn0, pd0, pn1, pd1, pn2, pd2, pn3, pd3;
            {
                v2f z0 = __builtin_elementwise_fma((v2f){ov0, ov1}, A2[0], B2[0]);
                v2f z1 = __builtin_elementwise_fma((v2f){ov2, ov3}, A2[1], B2[1]);
                v2f t0 = {__builtin_amdgcn_exp2f(z0.x), __builtin_amdgcn_exp2f(z0.y)};
                v2f t1 = {__builtin_amdgcn_exp2f(z1.x), __builtin_amdgcn_exp2f(z1.y)};
                t0 = t0 + 1.0f;  t1 = t1 + 1.0f;
                float s0 = __builtin_amdgcn_rcpf(t0.x);
                float s1x = __builtin_amdgcn_rcpf(t0.y);
                float s2 = __builtin_amdgcn_rcpf(t1.x);
                float s3 = __builtin_amdgcn_rcpf(t1.y);
                pn0 = fmaf(We[0], s0, fmaf(We[1], s1x, fmaf(We[2], s2, We[3] * s3)));
                pd0 = fmaf(Wr[0], s0, fmaf(Wr[1], s1x, fmaf(Wr[2], s2, Wr[3] * s3)));
            }
#define QUAD(D, RV, PN, PD)                                                     \
            {                                                                   \
                v2f z0 = __builtin_elementwise_fma((v2f){RV.x, RV.y},           \
                                                   A2[2*(D)], B2[2*(D)]);       \
                v2f z1 = __builtin_elementwise_fma((v2f){RV.z, RV.w},           \
                                                   A2[2*(D)+1], B2[2*(D)+1]);   \
                v2f t0 = {__builtin_amdgcn_exp2f(z0.x),                         \
                          __builtin_amdgcn_exp2f(z0.y)};                        \
                v2f t1 = {__builtin_amdgcn_exp2f(z1.x),                         \
                          __builtin_amdgcn_exp2f(z1.y)};                        \
                t0 = t0 + 1.0f;  t1 = t1 + 1.0f;                                \
                float s0 = __builtin_amdgcn_rcpf(t0.x);                         \
                float s1x = __builtin_amdgcn_rcpf(t0.y);                        \
                float s2 = __builtin_amdgcn_rcpf(t1.x);                         \
                float s3 = __builtin_amdgcn_rcpf(t1.y);                         \
                PN = fmaf(We[4*(D)], s0, fmaf(We[4*(D)+1], s1x,                 \
                     fmaf(We[4*(D)+2], s2, We[4*(D)+3] * s3)));                 \
                PD = fmaf(Wr[4*(D)], s0, fmaf(Wr[4*(D)+1], s1x,                 \
                     fmaf(Wr[4*(D)+2], s2, Wr[4*(D)+3] * s3)));                 \
            }
            QUAD(1, r1, pn1, pd1)
            QUAD(2, r2, pn2, pd2)
            QUAD(3, r3, pn3, pd3)
#undef QUAD
            float pn = (pn0 + pn1) + (pn2 + pn3);
            float pd = (pd0 + pd1) + (pd2 + pd3);

            // VALU butterfly over cc (lane bits 4,5): full column sums
            pn = red16(pn);  pd = red16(pd);
            pn = red32(pn);  pd = red32(pd);

            v_my = (cv + pn) * __builtin_amdgcn_rcpf(dbs + pd);

            // publish v: LDS for remote waves, bpermute for own quad (both
            // latencies hide under the drain+barrier window)
            if (lane < 16) vbuf[p ^ 1][(w << 4) + lane] = v_my;
            ov0 = bperm(bp0, v_my);
            ov1 = bperm(bp1, v_my);
            ov2 = bperm(bp2, v_my);
            ov3 = bperm(bp3, v_my);
            cv  = fmaf(cmt, v_my, nbs);   // next unfold's numerator base

            lds_barrier();
        }

        // rotate prefetched inputs; motor outputs from lanes 0..2 of wave 0
        xc[0] = p01.x; xc[1] = p01.y; xc[2] = p23.x;
        xc[3] = p23.y; xc[4] = p45.x; xc[5] = p45.y;
        if (t < MOT_) ob[s * MOT_ + t] = fmaf(v_my, OW, OB);
    }
}

extern "C" void kernel_launch(void* const* d_in, const int* in_sizes, int n_in,
                              void* d_out, int out_size, void* d_ws, size_t ws_size,
                              hipStream_t stream) {
    (void)in_sizes; (void)n_in; (void)d_ws; (void)ws_size; (void)out_size;
    const float* x       = (const float*)d_in[0];
    const float* mean_us = (const float*)d_in[1];
    const float* std_us  = (const float*)d_in[2];
    const float* input_w = (const float*)d_in[3];
    const float* input_b = (const float*)d_in[4];
    const float* out_w   = (const float*)d_in[5];
    const float* out_b   = (const float*)d_in[6];
    const float* gleak   = (const float*)d_in[7];
    const float* vleak   = (const float*)d_in[8];
    const float* cm      = (const float*)d_in[9];
    const float* sW      = (const float*)d_in[10];
    const float* sMu     = (const float*)d_in[11];
    const float* sSig    = (const float*)d_in[12];
    const float* sErev   = (const float*)d_in[13];
    const float* W       = (const float*)d_in[14];
    const float* Mu      = (const float*)d_in[15];
    const float* Sig     = (const float*)d_in[16];
    const float* Erev    = (const float*)d_in[17];
    float* out = (float*)d_out;

    ltc_kernel<<<dim3(B_), dim3(256), 0, stream>>>(
        x, mean_us, std_us, input_w, input_b, out_w, out_b,
        gleak, vleak, cm, sW, sMu, sSig, sErev, W, Mu, Sig, Erev, out);
}

// Round 12
// 9248.695 us; speedup vs baseline: 1.6450x; 1.0723x over previous
//
#include <hip/hip_runtime.h>

#define B_ 128
#define S_ 4096
#define IN_ 6
#define N_ 64
#define MOT_ 3
#define UNF 6
#define EPS_ 1e-8f
#define LOG2E 1.4426950408889634f

typedef float v2f __attribute__((ext_vector_type(2)));

// ---- VALU-pipe cross-lane pair-sums over lane bits 4 and 5 ----
__device__ __forceinline__ float red16(float x) {
#if __has_builtin(__builtin_amdgcn_permlane16_swap)
    auto r = __builtin_amdgcn_permlane16_swap(__float_as_int(x), __float_as_int(x),
                                              false, false);
    return __int_as_float((int)r[0]) + __int_as_float((int)r[1]);
#else
    return x + __shfl_xor(x, 16, 64);
#endif
}
__device__ __forceinline__ float red32(float x) {
#if __has_builtin(__builtin_amdgcn_permlane32_swap)
    auto r = __builtin_amdgcn_permlane32_swap(__float_as_int(x), __float_as_int(x),
                                              false, false);
    return __int_as_float((int)r[0]) + __int_as_float((int)r[1]);
#else
    return x + __shfl_xor(x, 32, 64);
#endif
}

// barrier with LDS-only drain (no vmcnt: global loads/stores stay in flight)
__device__ __forceinline__ void lds_barrier() {
    asm volatile("s_waitcnt lgkmcnt(0)" ::: "memory");
    __builtin_amdgcn_s_barrier();
}

// One workgroup per batch chain. 256 threads = 4 waves = 1 wave/SIMD.
// Wave w owns columns w*16..w*16+15; lane l = (cc=l>>4 j-chunk of 16, ii=l&15
// col). Per unfold: 16 sigmoids/lane (packed-f32 arg/add math), 4-way split
// accumulators SEEDED with 0.25*nbs / 0.25*dbs (the 4 butterfly partners sum
// the seeds back to nbs/dbs, removing the post-butterfly adds from the serial
// tail), 2-stage VALU butterfly (permlane16/32_swap), update
// v = fma(cmt,v,pn)*rcp(pd), ONE lgkm-only barrier. Sensory per-lane in
// registers at step start (r9 structure — measured best, 897 cy/unfold).
__launch_bounds__(256, 1)
__global__ void ltc_kernel(
    const float* __restrict__ x,
    const float* __restrict__ mean_us, const float* __restrict__ std_us,
    const float* __restrict__ input_w, const float* __restrict__ input_b,
    const float* __restrict__ output_w, const float* __restrict__ output_b,
    const float* __restrict__ gleak, const float* __restrict__ vleak,
    const float* __restrict__ cm,
    const float* __restrict__ sW, const float* __restrict__ sMu,
    const float* __restrict__ sSig, const float* __restrict__ sErev,
    const float* __restrict__ W, const float* __restrict__ Mu,
    const float* __restrict__ Sig, const float* __restrict__ Erev,
    float* __restrict__ out)
{
    const int b    = blockIdx.x;
    const int t    = threadIdx.x;
    const int lane = t & 63;
    const int w    = t >> 6;      // wave 0..3
    const int cc   = lane >> 4;   // j-chunk 0..3 (16 j's each)
    const int ii   = lane & 15;   // column within wave's block
    const int myCol = (w << 4) + ii;
    const int jb   = cc << 4;

    __shared__ __align__(16) float vbuf[2][N_];

    // --- recurrent synapse params: 16 synapses (j=jb..jb+15) of column myCol,
    // packed in pairs for v_pk_fma: sigmoid((v-mu)*sig) = 1/(1+exp2(v*A + Bc))
    v2f A2[8], B2[8];
    float Wr[16], We[16];
#pragma unroll
    for (int jj = 0; jj < 16; ++jj) {
        int idx = (jb + jj) * N_ + myCol;
        float sg = Sig[idx], m = Mu[idx], ww = W[idx], e = Erev[idx];
        A2[jj >> 1][jj & 1] = -sg * LOG2E;
        B2[jj >> 1][jj & 1] = m * sg * LOG2E;
        Wr[jj] = ww;
        We[jj] = ww * e;
    }

    // --- per-column state consts ---
    const float cmt = cm[myCol] * (float)UNF;
    const float glk = gleak[myCol];
    const float gv  = glk * vleak[myCol];
    const float dbase = cmt + glk + EPS_;

    // --- sensory params: per-lane, ALL 6 inputs for column myCol ---
    float SA[IN_], SB[IN_], SWe[IN_], SWv[IN_], NS[IN_], NB[IN_];
#pragma unroll
    for (int ci = 0; ci < IN_; ++ci) {
        int idx = ci * N_ + myCol;
        float sg = sSig[idx], m = sMu[idx], ww = sW[idx], e = sErev[idx];
        SA[ci]  = -sg * LOG2E;
        SB[ci]  = m * sg * LOG2E;
        SWv[ci] = ww;
        SWe[ci] = ww * e;
        NS[ci]  = input_w[ci] / std_us[ci];
        NB[ci]  = input_b[ci] - mean_us[ci] / std_us[ci] * input_w[ci];
    }

    // --- output consts (lanes 0..2 of wave 0 hold motor columns 0..2) ---
    float OW = 0.f, OB = 0.f;
    if (t < MOT_) {
        OW = output_w[t] * std_us[t];
        OB = output_b[t] * std_us[t] + mean_us[t];
    }

    const float* xb = x + (size_t)b * S_ * IN_;
    float* ob = out + (size_t)b * S_ * MOT_;

    if (t < N_) vbuf[0][t] = 0.f;

    // step-0 inputs (blocking, one-time); force VMEM via VGPR offset
    float xc[IN_];
    {
        int off = 0;
        asm volatile("" : "+v"(off));
        float2 x01 = *(const float2*)(xb + off);
        float2 x23 = *(const float2*)(xb + off + 2);
        float2 x45 = *(const float2*)(xb + off + 4);
        xc[0] = x01.x; xc[1] = x01.y; xc[2] = x23.x;
        xc[3] = x23.y; xc[4] = x45.x; xc[5] = x45.y;
    }
    __syncthreads();

    float v_my = 0.f;

    for (int s = 0; s < S_; ++s) {
        // prefetch next step's inputs (VMEM, stays in flight across lgkm waits)
        const int s1 = (s + 1 < S_) ? (s + 1) : s;
        int off = s1 * IN_;
        asm volatile("" : "+v"(off));
        float2 p01 = *(const float2*)(xb + off);
        float2 p23 = *(const float2*)(xb + off + 2);
        float2 p45 = *(const float2*)(xb + off + 4);

        // per-lane sensory fold for this step (registers only; overlaps k=0's
        // v-read + sigmoid phase, consumed only after k=0's butterfly)
        float wns = 0.f, wds = 0.f;
#pragma unroll
        for (int ci = 0; ci < IN_; ++ci) {
            float u  = fmaf(xc[ci], NS[ci], NB[ci]);
            float e  = __builtin_amdgcn_exp2f(fmaf(u, SA[ci], SB[ci]));
            float sg = __builtin_amdgcn_rcpf(1.0f + e);
            wns = fmaf(SWe[ci], sg, wns);
            wds = fmaf(SWv[ci], sg, wds);
        }
        // accumulator seeds: butterfly sums 4 partials -> 4 * 0.25 * base = base
        const float nseed = 0.25f * (gv + wns);
        const float dseed = 0.25f * (dbase + wds);

#pragma unroll
        for (int k = 0; k < UNF; ++k) {
            const int p = k & 1;
            // broadcast-read the 16 v's of this lane's j-chunk (4x ds_read_b128)
            float4 q0 = *(const float4*)&vbuf[p][jb];
            float4 q1 = *(const float4*)&vbuf[p][jb + 4];
            float4 q2 = *(const float4*)&vbuf[p][jb + 8];
            float4 q3 = *(const float4*)&vbuf[p][jb + 12];
            const v2f vp[8] = {
                {q0.x, q0.y}, {q0.z, q0.w}, {q1.x, q1.y}, {q1.z, q1.w},
                {q2.x, q2.y}, {q2.z, q2.w}, {q3.x, q3.y}, {q3.z, q3.w}};

            float pn0 = nseed, pd0 = dseed, pn1 = 0.f, pd1 = 0.f;
#pragma unroll
            for (int pi = 0; pi < 8; ++pi) {
                v2f z  = __builtin_elementwise_fma(vp[pi], A2[pi], B2[pi]); // pk_fma
                v2f e  = {__builtin_amdgcn_exp2f(z.x), __builtin_amdgcn_exp2f(z.y)};
                v2f tt = e + 1.0f;                                          // pk_add
                float s0  = __builtin_amdgcn_rcpf(tt.x);
                float s1x = __builtin_amdgcn_rcpf(tt.y);
                pn0 = fmaf(We[2*pi],   s0,  pn0);
                pd0 = fmaf(Wr[2*pi],   s0,  pd0);
                pn1 = fmaf(We[2*pi+1], s1x, pn1);
                pd1 = fmaf(Wr[2*pi+1], s1x, pd1);
            }
            float pn = pn0 + pn1;
            float pd = pd0 + pd1;

            // VALU butterfly over cc (lane bits 4,5): full column sums
            // (seeds sum back to nbs/dbs exactly: 4 equal power-of-2 fractions)
            pn = red16(pn);  pd = red16(pd);
            pn = red32(pn);  pd = red32(pd);

            // shortened tail: fma || rcp, then one mul
            v_my = fmaf(cmt, v_my, pn) * __builtin_amdgcn_rcpf(pd);

            // publish v for next unfold (double-buffered, one writer per column)
            if (lane < 16) vbuf[p ^ 1][(w << 4) + lane] = v_my;

            lds_barrier();
        }

        // rotate prefetched inputs; motor outputs from lanes 0..2 of wave 0
        xc[0] = p01.x; xc[1] = p01.y; xc[2] = p23.x;
        xc[3] = p23.y; xc[4] = p45.x; xc[5] = p45.y;
        if (t < MOT_) ob[s * MOT_ + t] = fmaf(v_my, OW, OB);
    }
}

extern "C" void kernel_launch(void* const* d_in, const int* in_sizes, int n_in,
                              void* d_out, int out_size, void* d_ws, size_t ws_size,
                              hipStream_t stream) {
    (void)in_sizes; (void)n_in; (void)d_ws; (void)ws_size; (void)out_size;
    const float* x       = (const float*)d_in[0];
    const float* mean_us = (const float*)d_in[1];
    const float* std_us  = (const float*)d_in[2];
    const float* input_w = (const float*)d_in[3];
    const float* input_b = (const float*)d_in[4];
    const float* out_w   = (const float*)d_in[5];
    const float* out_b   = (const float*)d_in[6];
    const float* gleak   = (const float*)d_in[7];
    const float* vleak   = (const float*)d_in[8];
    const float* cm      = (const float*)d_in[9];
    const float* sW      = (const float*)d_in[10];
    const float* sMu     = (const float*)d_in[11];
    const float* sSig    = (const float*)d_in[12];
    const float* sErev   = (const float*)d_in[13];
    const float* W       = (const float*)d_in[14];
    const float* Mu      = (const float*)d_in[15];
    const float* Sig     = (const float*)d_in[16];
    const float* Erev    = (const float*)d_in[17];
    float* out = (float*)d_out;

    ltc_kernel<<<dim3(B_), dim3(256), 0, stream>>>(
        x, mean_us, std_us, input_w, input_b, out_w, out_b,
        gleak, vleak, cm, sW, sMu, sSig, sErev, W, Mu, Sig, Erev, out);
}